// Round 7
// baseline (482.890 us; speedup 1.0000x reference)
//
#include <hip/hip_runtime.h>
#include <stdint.h>

#define LR     10000
#define NV     (LR >> 2)       // 2500 float4s per row
#define MTOP   50
#define LOG2E  1.4426950408889634f
#define CAP    512             // candidate buffer (compact+finish threshold)
#define PIDX(b) ((((b) >> 4) * 17) + ((b) & 15))
#define HW256  (16 * 17)       // padded 256-bin hist words

// ---------------- common wave-parallel rank-pick ----------------
// Rank-pick over 16 values held by lanes 0..15 (lanes>=16 hold 0), scanning
// from idx 15 down; updates rem to residual within the picked idx. Wave 0 only.
__device__ __forceinline__ int pick16(uint32_t v, int lane, int& rem) {
    uint32_t sfx = v;
    #pragma unroll
    for (int off = 1; off < 16; off <<= 1) {
        uint32_t t = __shfl_down(sfx, off);
        if (lane + off < 16) sfx += t;
    }
    bool p = (lane < 16) && ((int)sfx >= rem);
    unsigned long long m = __ballot(p);
    int idx = 63 - __builtin_clzll(m);
    uint32_t sfx_at = __shfl(sfx, idx);
    uint32_t v_at   = __shfl(v,   idx);
    rem -= (int)(sfx_at - v_at);
    return idx;
}

// Rank-select over a padded 256-bin hist (layout PIDX). In: *rem. Out: *bin, *rem.
__device__ void sel256(uint32_t* hist, int* bin, int* rem, int tid) {
    if (tid < 64) {
        const int lane = tid;
        int r = *rem;
        uint32_t sup = 0;
        if (lane < 16) {
            #pragma unroll
            for (int j = 0; j < 16; ++j) sup += hist[lane * 17 + j];
        }
        const int s1 = pick16(sup, lane, r);
        const uint32_t h = (lane < 16) ? hist[s1 * 17 + lane] : 0;
        const int s2 = pick16(h, lane, r);
        if (lane == 0) { *bin = (s1 << 4) + s2; *rem = r; }
    }
    __syncthreads();
}

// ================= K1: pure stream — bce keys + per-row 256-bin hist =========
__global__ __launch_bounds__(512)
void k1_stream(const float* __restrict__ logits, const float* __restrict__ targets,
               uint32_t* __restrict__ keys_ws, uint32_t* __restrict__ hist_ws)
{
    __shared__ uint32_t h[256];
    const int tid = threadIdx.x;
    const int row = blockIdx.x;
    const size_t base = (size_t)row * LR;
    const float4* lg = (const float4*)(logits + base);
    const float4* tg = (const float4*)(targets + base);
    uint4* ko = (uint4*)(keys_ws + base);

    if (tid < 256) h[tid] = 0;
    __syncthreads();

    #pragma unroll
    for (int k = 0; k < 5; ++k) {
        const int i = tid + k * 512;
        const bool ok = (i < NV);
        const int ii = ok ? i : (NV - 1);
        const float4 x = lg[ii];
        const float4 t = tg[ii];
        const float xv[4] = {x.x, x.y, x.z, x.w};
        const float tv[4] = {t.x, t.y, t.z, t.w};
        uint32_t kk[4];
        #pragma unroll
        for (int j = 0; j < 4; ++j) {
            // bce/ln2 = log2(1 + 2^u), u = (t ? -x : x) * log2e; always >= 0,
            // so raw float bits are the monotonic sort key.
            const float u = xv[j] * (tv[j] != 0.0f ? -LOG2E : LOG2E);
            kk[j] = __float_as_uint(__log2f(1.0f + __builtin_amdgcn_exp2f(u)));
        }
        if (ok) {
            ko[i] = make_uint4(kk[0], kk[1], kk[2], kk[3]);
            #pragma unroll
            for (int j = 0; j < 4; ++j) atomicAdd(&h[kk[j] >> 23], 1u);
        }
    }
    __syncthreads();
    if (tid < 256) hist_ws[(size_t)row * 256 + tid] = h[tid];
}

// ================= K2: per-row select from precomputed keys+hist =============
struct S2 {
    uint32_t hist[HW256];
    uint32_t cand[CAP];
    int cc, bin, rem;
    float wsum[16];
};

__global__ __launch_bounds__(1024)
void k2_select(const uint32_t* __restrict__ keys_ws, const uint32_t* __restrict__ hist_ws,
               float* __restrict__ out, float scale)
{
    __shared__ S2 S;
    const int tid = threadIdx.x;
    const int row = blockIdx.x;
    const uint4* kp = (const uint4*)(keys_ws + (size_t)row * LR);

    const uint4 a0 = kp[tid];
    const uint4 a1 = kp[tid + 1024];
    const uint4 a2 = kp[min(tid + 2048, NV - 1)];
    const bool ok2 = (tid + 2048) < NV;
    uint32_t kk[12] = {a0.x, a0.y, a0.z, a0.w,
                       a1.x, a1.y, a1.z, a1.w,
                       a2.x, a2.y, a2.z, a2.w};

    if (tid < 256) S.hist[PIDX(tid)] = hist_ws[(size_t)row * 256 + tid];
    if (tid == 0) { S.rem = MTOP; S.cc = 0; }
    __syncthreads();

    // Level 1: select among 256 exponent bins (hist from K1).
    sel256(S.hist, &S.bin, &S.rem, tid);

    uint32_t pref = (uint32_t)S.bin;   // key>>shift == pref for boundary bucket
    int      shift = 23;
    uint32_t prevPref = 0;             // key>>prevShift == prevPref (outer prefix)
    int      prevShift = 31;           // key>>31 == 0 always (bce2 >= 0)
    int      rem = S.rem;
    uint32_t cnt = S.hist[PIDX(pref)];
    float    sure = 0.0f;              // sum of keys proven in top-MTOP

    // Refine 8 bits at a time until the boundary bucket is small.
    while (cnt > CAP && shift > 0) {
        const int nshift = (shift >= 8) ? (shift - 8) : 0;
        const uint32_t dmask = (1u << (shift - nshift)) - 1u;
        if (tid < HW256) S.hist[tid] = 0;
        __syncthreads();
        #pragma unroll
        for (int k = 0; k < 12; ++k) {
            const bool ok = (k < 8) || ok2;
            const uint32_t key = kk[k];
            if (ok) {
                const uint32_t hi = key >> shift;
                if (hi == pref) {
                    atomicAdd(&S.hist[PIDX((key >> nshift) & dmask)], 1u);
                } else if (hi > pref && (key >> prevShift) == prevPref) {
                    sure += __uint_as_float(key);   // newly-proven top element
                }
            }
        }
        __syncthreads();
        sel256(S.hist, &S.bin, &S.rem, tid);
        const uint32_t b = (uint32_t)S.bin;
        rem = S.rem;
        cnt = S.hist[PIDX(b)];
        prevPref = pref; prevShift = shift;
        pref = (pref << (shift - nshift)) | b;
        shift = nshift;
    }

    if (cnt <= CAP) {
        // Compact boundary-bucket keys + add this level's newly-sure keys.
        #pragma unroll
        for (int k = 0; k < 12; ++k) {
            const bool ok = (k < 8) || ok2;
            const uint32_t key = kk[k];
            if (ok) {
                const uint32_t hi = key >> shift;
                if (hi == pref) {
                    const int idx = atomicAdd(&S.cc, 1);
                    if (idx < CAP) S.cand[idx] = key;
                } else if (hi > pref && (key >> prevShift) == prevPref) {
                    sure += __uint_as_float(key);
                }
            }
        }
        __syncthreads();
        const int C = S.cc;            // exact == cnt <= CAP
        if (tid < C) {
            // Exact rank-count finish with tie handling (broadcast LDS reads).
            const uint32_t v = S.cand[tid];
            int g = 0, e = 0;
            for (int j = 0; j < C; ++j) {
                const uint32_t w = S.cand[j];
                g += (w > v);
                e += (w == v && j < tid);
            }
            if (g < rem && (rem - g) > e) sure += __uint_as_float(v);
        }
    } else {
        // shift==0 and still >CAP: all remaining matches share all 31 key bits
        // (exactly equal values). Add newly-sure keys, then rem copies of value.
        #pragma unroll
        for (int k = 0; k < 12; ++k) {
            const bool ok = (k < 8) || ok2;
            const uint32_t key = kk[k];
            if (ok && key > pref && (key >> prevShift) == prevPref)
                sure += __uint_as_float(key);
        }
        if (tid == 0) sure += (float)rem * __uint_as_float(pref);
    }

    // Block reduce + one global atomic per row.
    #pragma unroll
    for (int off = 32; off > 0; off >>= 1) sure += __shfl_down(sure, off);
    const int wid = tid >> 6;
    if ((tid & 63) == 0) S.wsum[wid] = sure;
    __syncthreads();
    if (tid == 0) {
        float tot = 0.0f;
        #pragma unroll
        for (int w = 0; w < 16; ++w) tot += S.wsum[w];
        atomicAdd(out, tot * scale);
    }
}

// ================= Fallback: proven single-kernel (r6, 129.6 us) =============
#define HWORDS (256 * 17)
#define SEGW   (16 * 17)

struct Shared {
    uint32_t hist[HWORDS];
    uint32_t segsum[SEGW];
    int bin, rem;
    float    wred[16];
    uint32_t wcnt[16];
};

__device__ void select4096(Shared& S, int tid) {
    if (tid < 256) {
        uint32_t s = 0;
        #pragma unroll
        for (int j = 0; j < 16; ++j) s += S.hist[tid * 17 + j];
        S.segsum[(tid >> 4) * 17 + (tid & 15)] = s;
    }
    __syncthreads();
    if (tid < 64) {
        const int lane = tid;
        int rem = S.rem;
        uint32_t sup = 0;
        if (lane < 16) {
            #pragma unroll
            for (int j = 0; j < 16; ++j) sup += S.segsum[lane * 17 + j];
        }
        const int s1 = pick16(sup, lane, rem);
        const uint32_t seg = (lane < 16) ? S.segsum[s1 * 17 + lane] : 0;
        const int s2 = pick16(seg, lane, rem);
        const int g = (s1 << 4) + s2;
        const uint32_t h = (lane < 16) ? S.hist[g * 17 + lane] : 0;
        const int s3 = pick16(h, lane, rem);
        if (lane == 0) { S.bin = (g << 4) + s3; S.rem = rem; }
    }
    __syncthreads();
}

__device__ void select256f(Shared& S, int tid) {
    if (tid < 64) {
        const int lane = tid;
        int rem = S.rem;
        uint32_t sup = 0;
        if (lane < 16) {
            #pragma unroll
            for (int j = 0; j < 16; ++j) sup += S.hist[lane * 17 + j];
        }
        const int s1 = pick16(sup, lane, rem);
        const uint32_t h = (lane < 16) ? S.hist[s1 * 17 + lane] : 0;
        const int s2 = pick16(h, lane, rem);
        if (lane == 0) { S.bin = (s1 << 4) + s2; S.rem = rem; }
    }
    __syncthreads();
}

__global__ __launch_bounds__(1024, 8)
void bce_topk_kernel(const float* __restrict__ logits,
                     const float* __restrict__ targets,
                     float* __restrict__ out,
                     int Lr, float scale)
{
    __shared__ Shared S;
    const int tid = threadIdx.x;
    const size_t rowbase = (size_t)blockIdx.x * (size_t)Lr;
    const float4* lg = (const float4*)(logits + rowbase);
    const float4* tg = (const float4*)(targets + rowbase);
    const int nv = Lr >> 2;

    for (int i = tid; i < HWORDS; i += 1024) S.hist[i] = 0;
    if (tid == 0) S.rem = MTOP;
    __syncthreads();

    const int i0 = tid, i1 = tid + 1024, i2 = tid + 2048;
    const int c0 = min(i0, nv - 1), c1 = min(i1, nv - 1), c2 = min(i2, nv - 1);
    const float4 l0 = lg[c0], l1 = lg[c1], l2 = lg[c2];
    const float4 t0 = tg[c0], t1 = tg[c1], t2 = tg[c2];

    uint32_t kk[3][4];
    #define COMPUTE_BATCH(K, LV, TV, OK)                                        \
    {                                                                           \
        const float xv[4] = {LV.x, LV.y, LV.z, LV.w};                           \
        const float tv[4] = {TV.x, TV.y, TV.z, TV.w};                           \
        _Pragma("unroll")                                                       \
        for (int j = 0; j < 4; ++j) {                                           \
            const float u = xv[j] * (tv[j] != 0.0f ? -LOG2E : LOG2E);           \
            const float bce2 = __log2f(1.0f + __builtin_amdgcn_exp2f(u));       \
            const uint32_t key = (OK) ? __float_as_uint(bce2) : 0u;             \
            kk[K][j] = key;                                                     \
            if (OK) atomicAdd(&S.hist[(key >> 24) * 17 + ((key >> 20) & 15)], 1u); \
        }                                                                       \
    }
    COMPUTE_BATCH(0, l0, t0, (i0 < nv));
    COMPUTE_BATCH(1, l1, t1, (i1 < nv));
    COMPUTE_BATCH(2, l2, t2, (i2 < nv));
    #undef COMPUTE_BATCH
    __syncthreads();

    select4096(S, tid);
    const uint32_t pref1 = (uint32_t)S.bin;

    for (int i = tid; i < HWORDS; i += 1024) S.hist[i] = 0;
    __syncthreads();
    #pragma unroll
    for (int k = 0; k < 3; ++k) {
        #pragma unroll
        for (int j = 0; j < 4; ++j) {
            const uint32_t key = kk[k][j];
            if ((key >> 20) == pref1)
                atomicAdd(&S.hist[((key >> 12) & 0xFFu) * 17 + ((key >> 8) & 15)], 1u);
        }
    }
    __syncthreads();
    select4096(S, tid);
    const uint32_t pref2 = (pref1 << 12) | (uint32_t)S.bin;

    for (int i = tid; i < SEGW; i += 1024) S.hist[i] = 0;
    __syncthreads();
    #pragma unroll
    for (int k = 0; k < 3; ++k) {
        #pragma unroll
        for (int j = 0; j < 4; ++j) {
            const uint32_t key = kk[k][j];
            if ((key >> 8) == pref2)
                atomicAdd(&S.hist[((key >> 4) & 15) * 17 + (key & 15)], 1u);
        }
    }
    __syncthreads();
    select256f(S, tid);
    const uint32_t K = (pref2 << 8) | (uint32_t)S.bin;

    float sum = 0.0f;
    uint32_t cnt = 0;
    #pragma unroll
    for (int k = 0; k < 3; ++k) {
        #pragma unroll
        for (int j = 0; j < 4; ++j) {
            const uint32_t key = kk[k][j];
            if (key > K) { sum += __uint_as_float(key); cnt++; }
        }
    }
    #pragma unroll
    for (int off = 32; off > 0; off >>= 1) {
        sum += __shfl_down(sum, off);
        cnt += __shfl_down(cnt, off);
    }
    const int wid = tid >> 6;
    if ((tid & 63) == 0) { S.wred[wid] = sum; S.wcnt[wid] = cnt; }
    __syncthreads();
    if (tid == 0) {
        float s = 0.0f; int c = 0;
        #pragma unroll
        for (int w = 0; w < 16; ++w) { s += S.wred[w]; c += (int)S.wcnt[w]; }
        const float tot = s + (float)(MTOP - c) * __uint_as_float(K);
        atomicAdd(out, tot * scale);
    }
}

// ================= host launcher =============================================
extern "C" void kernel_launch(void* const* d_in, const int* in_sizes, int n_in,
                              void* d_out, int out_size, void* d_ws, size_t ws_size,
                              hipStream_t stream) {
    const float* logits  = (const float*)d_in[0];
    const float* targets = (const float*)d_in[1];
    float* out = (float*)d_out;

    const int B = in_sizes[0] / LR;
    // keys are bce/ln2; fold ln2 into the final scale
    const float scale = 0.69314718055994531f / ((float)MTOP * (float)B);

    hipMemsetAsync(out, 0, sizeof(float), stream);

    const size_t need = (size_t)B * LR * sizeof(uint32_t)
                      + (size_t)B * 256 * sizeof(uint32_t);
    if (ws_size >= need) {
        uint32_t* keys_ws = (uint32_t*)d_ws;
        uint32_t* hist_ws = keys_ws + (size_t)B * LR;
        k1_stream<<<B, 512, 0, stream>>>(logits, targets, keys_ws, hist_ws);
        k2_select<<<B, 1024, 0, stream>>>(keys_ws, hist_ws, out, scale);
    } else {
        bce_topk_kernel<<<B, 1024, 0, stream>>>(logits, targets, out, LR, scale);
    }
}

// Round 8
// 329.016 us; speedup vs baseline: 1.4677x; 1.4677x over previous
//
#include <hip/hip_runtime.h>
#include <stdint.h>

#define TPB    1024
#define MTOP   50
#define LOG2E  1.4426950408889634f
#define HWORDS (256 * 17)     // 4096-bin hist, padded [256 groups][16+1]
#define SEGW   (16 * 17)      // padded 256 segment sums
#define CAP    1024           // candidate buffer for exact finish
#define PIDX(b) ((((b) >> 4) * 17) + ((b) & 15))

struct Shared {
    uint32_t hist[HWORDS];
    uint32_t segsum[SEGW];
    uint32_t cand[CAP];
    int bin, rem, cc;
    float wred[16];
};

// Wave-parallel rank-pick over 16 values held by lanes 0..15 (lanes>=16 hold 0),
// scanning from idx 15 down; updates rem to residual within the picked idx.
__device__ __forceinline__ int pick16(uint32_t v, int lane, int& rem) {
    uint32_t sfx = v;
    #pragma unroll
    for (int off = 1; off < 16; off <<= 1) {
        uint32_t t = __shfl_down(sfx, off);
        if (lane + off < 16) sfx += t;
    }
    bool p = (lane < 16) && ((int)sfx >= rem);
    unsigned long long m = __ballot(p);
    int idx = 63 - __builtin_clzll(m);
    uint32_t sfx_at = __shfl(sfx, idx);
    uint32_t v_at   = __shfl(v,   idx);
    rem -= (int)(sfx_at - v_at);
    return idx;
}

// Rank-select over the padded 4096-bin hist. In: S.rem. Out: S.bin, S.rem.
__device__ void select4096(Shared& S, int tid) {
    if (tid < 256) {
        uint32_t s = 0;
        #pragma unroll
        for (int j = 0; j < 16; ++j) s += S.hist[tid * 17 + j];   // stride-17: conflict-free
        S.segsum[(tid >> 4) * 17 + (tid & 15)] = s;
    }
    __syncthreads();
    if (tid < 64) {
        const int lane = tid;
        int rem = S.rem;
        uint32_t sup = 0;
        if (lane < 16) {
            #pragma unroll
            for (int j = 0; j < 16; ++j) sup += S.segsum[lane * 17 + j];
        }
        const int s1 = pick16(sup, lane, rem);
        const uint32_t seg = (lane < 16) ? S.segsum[s1 * 17 + lane] : 0;
        const int s2 = pick16(seg, lane, rem);
        const int g = (s1 << 4) + s2;
        const uint32_t h = (lane < 16) ? S.hist[g * 17 + lane] : 0;
        const int s3 = pick16(h, lane, rem);
        if (lane == 0) { S.bin = (g << 4) + s3; S.rem = rem; }
    }
    __syncthreads();
}

// Rank-select over 256 bins stored at PIDX (groups 0..15).
__device__ void select256b(Shared& S, int tid) {
    if (tid < 64) {
        const int lane = tid;
        int rem = S.rem;
        uint32_t sup = 0;
        if (lane < 16) {
            #pragma unroll
            for (int j = 0; j < 16; ++j) sup += S.hist[lane * 17 + j];
        }
        const int s1 = pick16(sup, lane, rem);
        const uint32_t h = (lane < 16) ? S.hist[s1 * 17 + lane] : 0;
        const int s2 = pick16(h, lane, rem);
        if (lane == 0) { S.bin = (s1 << 4) + s2; S.rem = rem; }
    }
    __syncthreads();
}

__global__ __launch_bounds__(TPB, 8)
void bce_topk_kernel(const float* __restrict__ logits,
                     const float* __restrict__ targets,
                     float* __restrict__ out,
                     int Lr, float scale)
{
    __shared__ Shared S;
    const int tid = threadIdx.x;
    const size_t rowbase = (size_t)blockIdx.x * (size_t)Lr;
    const float4* lg = (const float4*)(logits + rowbase);
    const float4* tg = (const float4*)(targets + rowbase);
    const int nv = Lr >> 2;   // 2500 float4s per row

    for (int i = tid; i < HWORDS; i += TPB) S.hist[i] = 0;
    if (tid == 0) { S.rem = MTOP; S.cc = 0; }
    __syncthreads();

    // ---- Pass 1: issue all 6 loads up-front, compute bce keys in registers,
    // histogram top-12 key bits. bce2 = log2(1 + 2^u), u = (t ? -x : x)*log2e;
    // bce2 >= 0 so raw float bits are the monotonic sort key (ln2 folded into scale).
    const int i0 = tid, i1 = tid + TPB, i2 = tid + 2 * TPB;
    const int c0 = min(i0, nv - 1), c1 = min(i1, nv - 1), c2 = min(i2, nv - 1);
    const float4 l0 = lg[c0], l1 = lg[c1], l2 = lg[c2];
    const float4 t0 = tg[c0], t1 = tg[c1], t2 = tg[c2];

    uint32_t kk[3][4];
    #define COMPUTE_BATCH(K, LV, TV, OK)                                        \
    {                                                                           \
        const float xv[4] = {LV.x, LV.y, LV.z, LV.w};                           \
        const float tv[4] = {TV.x, TV.y, TV.z, TV.w};                           \
        _Pragma("unroll")                                                       \
        for (int j = 0; j < 4; ++j) {                                           \
            const float u = xv[j] * (tv[j] != 0.0f ? -LOG2E : LOG2E);           \
            const float bce2 = __log2f(1.0f + __builtin_amdgcn_exp2f(u));       \
            const uint32_t key = (OK) ? __float_as_uint(bce2) : 0u;             \
            kk[K][j] = key;                                                     \
            if (OK) atomicAdd(&S.hist[(key >> 24) * 17 + ((key >> 20) & 15)], 1u); \
        }                                                                       \
    }
    COMPUTE_BATCH(0, l0, t0, (i0 < nv));
    COMPUTE_BATCH(1, l1, t1, (i1 < nv));
    COMPUTE_BATCH(2, l2, t2, (i2 < nv));
    #undef COMPUTE_BATCH
    __syncthreads();

    // ---- Select among 4096 bins (12-bit prefix). Boundary bucket ~25 keys here.
    select4096(S, tid);
    const uint32_t pref1 = (uint32_t)S.bin;

    // ---- One register scan: sure-sum (bins above) + compact boundary bucket.
    float sum = 0.0f;
    #pragma unroll
    for (int k = 0; k < 3; ++k) {
        #pragma unroll
        for (int j = 0; j < 4; ++j) {
            const uint32_t key = kk[k][j];
            const uint32_t hi = key >> 20;
            if (hi > pref1) {
                sum += __uint_as_float(key);
            } else if (hi == pref1) {
                const int idx = atomicAdd(&S.cc, 1);
                if (idx < CAP) S.cand[idx] = key;
            }
        }
    }
    __syncthreads();

    int C   = S.cc;
    int rem = S.rem;
    bool finish = (C <= CAP);

    if (!finish) {
        // ---- Fallback A (rare): refine bits 19..8 with a second 4096-bin hist.
        for (int i = tid; i < HWORDS; i += TPB) S.hist[i] = 0;
        __syncthreads();
        #pragma unroll
        for (int k = 0; k < 3; ++k) {
            #pragma unroll
            for (int j = 0; j < 4; ++j) {
                const uint32_t key = kk[k][j];
                if ((key >> 20) == pref1) {
                    const uint32_t mid = (key >> 8) & 0xFFFu;
                    atomicAdd(&S.hist[PIDX(mid)], 1u);
                }
            }
        }
        __syncthreads();
        select4096(S, tid);
        const uint32_t bin2 = (uint32_t)S.bin;
        rem = S.rem;
        const uint32_t cnt2 = S.hist[PIDX(bin2)];
        if (tid == 0) S.cc = 0;
        __syncthreads();

        if (cnt2 <= CAP) {
            #pragma unroll
            for (int k = 0; k < 3; ++k) {
                #pragma unroll
                for (int j = 0; j < 4; ++j) {
                    const uint32_t key = kk[k][j];
                    if ((key >> 20) == pref1) {
                        const uint32_t mid = (key >> 8) & 0xFFFu;
                        if (mid > bin2) {
                            sum += __uint_as_float(key);
                        } else if (mid == bin2) {
                            const int idx = atomicAdd(&S.cc, 1);
                            if (idx < CAP) S.cand[idx] = key;
                        }
                    }
                }
            }
            __syncthreads();
            C = S.cc;
            finish = true;
        } else {
            // ---- Fallback B (essentially impossible): refine last 8 bits; all
            // remaining bucket keys are then exactly equal.
            const uint32_t pref2 = (pref1 << 12) | bin2;
            for (int i = tid; i < SEGW; i += TPB) S.hist[i] = 0;
            __syncthreads();
            #pragma unroll
            for (int k = 0; k < 3; ++k) {
                #pragma unroll
                for (int j = 0; j < 4; ++j) {
                    const uint32_t key = kk[k][j];
                    if ((key >> 8) == pref2)
                        atomicAdd(&S.hist[PIDX(key & 0xFFu)], 1u);
                }
            }
            __syncthreads();
            select256b(S, tid);
            const uint32_t bin3 = (uint32_t)S.bin;
            rem = S.rem;
            #pragma unroll
            for (int k = 0; k < 3; ++k) {
                #pragma unroll
                for (int j = 0; j < 4; ++j) {
                    const uint32_t key = kk[k][j];
                    if ((key >> 8) == pref2 && (key & 0xFFu) > bin3)
                        sum += __uint_as_float(key);
                }
            }
            if (tid == 0)
                sum += (float)rem * __uint_as_float((pref2 << 8) | bin3);
        }
    }

    if (finish) {
        // ---- Exact rank/tie finish over C candidates (C small; LDS broadcasts).
        if (tid < C) {
            const uint32_t v = S.cand[tid];
            int g = 0, e = 0;
            for (int j = 0; j < C; ++j) {
                const uint32_t w = S.cand[j];
                g += (w > v);
                e += (w == v && j < tid);
            }
            if (g + e < rem) sum += __uint_as_float(v);
        }
    }

    // ---- Block reduce + one global atomic per row.
    #pragma unroll
    for (int off = 32; off > 0; off >>= 1) sum += __shfl_down(sum, off);
    const int wid = tid >> 6;
    if ((tid & 63) == 0) S.wred[wid] = sum;
    __syncthreads();
    if (tid == 0) {
        float tot = 0.0f;
        #pragma unroll
        for (int w = 0; w < 16; ++w) tot += S.wred[w];
        atomicAdd(out, tot * scale);
    }
}

extern "C" void kernel_launch(void* const* d_in, const int* in_sizes, int n_in,
                              void* d_out, int out_size, void* d_ws, size_t ws_size,
                              hipStream_t stream) {
    const float* logits  = (const float*)d_in[0];
    const float* targets = (const float*)d_in[1];
    float* out = (float*)d_out;

    const int Lr = 10000;
    const int B  = in_sizes[0] / Lr;
    // keys are bce/ln2; fold ln2 into the final scale
    const float scale = 0.69314718055994531f / ((float)MTOP * (float)B);

    hipMemsetAsync(out, 0, sizeof(float), stream);
    bce_topk_kernel<<<B, TPB, 0, stream>>>(logits, targets, out, Lr, scale);
}